// Round 13
// baseline (407.271 us; speedup 1.0000x reference)
//
#include <hip/hip_runtime.h>
#include <math.h>

#define H 256

typedef __attribute__((ext_vector_type(8))) short short8;
typedef __attribute__((ext_vector_type(4))) float f32x4;
typedef __attribute__((ext_vector_type(4))) int int4v;
typedef __attribute__((ext_vector_type(2))) unsigned int uint2v;
typedef unsigned short ushort_t;

__device__ __forceinline__ float bf2f(unsigned short u) {
    union { unsigned int i; float f; } v; v.i = ((unsigned int)u) << 16; return v.f;
}
__device__ __forceinline__ unsigned short f2bf(float f) {
    union { float f; unsigned int i; } v; v.f = f;
    unsigned int r = v.i + 0x7FFFu + ((v.i >> 16) & 1u);   // RNE
    return (unsigned short)(r >> 16);
}
__device__ __forceinline__ void glds16(const void* g, void* l) {
    __builtin_amdgcn_global_load_lds((const __attribute__((address_space(1))) void*)g,
                                     (__attribute__((address_space(3))) void*)l, 16, 0, 0);
}
__device__ __forceinline__ int4v pack_f32x8_bf16(const float* p) {
    float4 f0 = *(const float4*)(p);
    float4 f1 = *(const float4*)(p + 4);
    int4v d;
    d.x = (int)((unsigned)f2bf(f0.x) | ((unsigned)f2bf(f0.y) << 16));
    d.y = (int)((unsigned)f2bf(f0.z) | ((unsigned)f2bf(f0.w) << 16));
    d.z = (int)((unsigned)f2bf(f1.x) | ((unsigned)f2bf(f1.y) << 16));
    d.w = (int)((unsigned)f2bf(f1.z) | ((unsigned)f2bf(f1.w) << 16));
    return d;
}

#define CONVB 2048

// ---------------- merged prep + segment-mean ----------------
// Blocks [0,CONVB): weights transpose+cast + x->bf16 (grid-stride, BW-bound).
// Blocks [CONVB,..): segment means gathered from fp32 x (latency-bound).
// The two families are independent; mixing them on the CUs lets gather-latency
// stalls hide under the streaming conversion's bandwidth work.
__global__ __launch_bounds__(256) void prep_seg(
    const float* __restrict__ Wm, const float* __restrict__ Wg,
    const float* __restrict__ Wu, const float* __restrict__ x,
    const int* __restrict__ ptr, const int* __restrict__ src,
    ushort_t* __restrict__ Wmt, ushort_t* __restrict__ Wgt,
    ushort_t* __restrict__ Wut,
    ushort_t* __restrict__ yb, ushort_t* __restrict__ smb,
    int R, int E, size_t n8)
{
    if (blockIdx.x < CONVB) {
        size_t gtid = (size_t)blockIdx.x * 256 + threadIdx.x;
        size_t stride = (size_t)CONVB * 256;
        for (size_t i = gtid; i < 65536; i += stride) {
            int n = (int)(i >> 8), k = (int)(i & 255);
            Wmt[i] = f2bf(Wm[(size_t)k * 256 + n]);
            Wut[i] = f2bf(Wu[(size_t)k * 256 + n]);
        }
        for (size_t i = gtid; i < 131072; i += stride) {
            int n = (int)(i >> 9), k = (int)(i & 511);
            Wgt[i] = f2bf(Wg[(size_t)k * 256 + n]);
        }
        for (size_t i = gtid; i < n8; i += stride)
            *(int4v*)(yb + i * 8) = pack_f32x8_bf16(x + i * 8);
        return;
    }
    // ---- segment mean: half-wave per edge, fp32 gather (2x16B per row) ----
    int e = (blockIdx.x - CONVB) * 8 + (threadIdx.x >> 5);
    if (e >= E) return;
    int lane = threadIdx.x & 31;
    const float* base = x + lane * 8;    // 8 cols per lane
    int s = ptr[e], t = ptr[e + 1];
    float a0 = 0.f, a1 = 0.f, a2 = 0.f, a3 = 0.f, a4 = 0.f, a5 = 0.f, a6 = 0.f, a7 = 0.f;
    int i = s;
    for (; i + 4 <= t; i += 4) {
        const float* p0 = base + (size_t)src[i + 0] * H;
        const float* p1 = base + (size_t)src[i + 1] * H;
        const float* p2 = base + (size_t)src[i + 2] * H;
        const float* p3 = base + (size_t)src[i + 3] * H;
        float4 l0 = *(const float4*)(p0), h0 = *(const float4*)(p0 + 4);
        float4 l1 = *(const float4*)(p1), h1 = *(const float4*)(p1 + 4);
        float4 l2 = *(const float4*)(p2), h2 = *(const float4*)(p2 + 4);
        float4 l3 = *(const float4*)(p3), h3 = *(const float4*)(p3 + 4);
        a0 += l0.x + l1.x + l2.x + l3.x;  a1 += l0.y + l1.y + l2.y + l3.y;
        a2 += l0.z + l1.z + l2.z + l3.z;  a3 += l0.w + l1.w + l2.w + l3.w;
        a4 += h0.x + h1.x + h2.x + h3.x;  a5 += h0.y + h1.y + h2.y + h3.y;
        a6 += h0.z + h1.z + h2.z + h3.z;  a7 += h0.w + h1.w + h2.w + h3.w;
    }
    for (; i < t; ++i) {
        const float* p = base + (size_t)src[i] * H;
        float4 lo = *(const float4*)(p), hi = *(const float4*)(p + 4);
        a0 += lo.x; a1 += lo.y; a2 += lo.z; a3 += lo.w;
        a4 += hi.x; a5 += hi.y; a6 += hi.z; a7 += hi.w;
    }
    float inv = 1.f / (float)(t - s);
    int4v o;
    o.x = (int)((unsigned)f2bf(a0 * inv) | ((unsigned)f2bf(a1 * inv) << 16));
    o.y = (int)((unsigned)f2bf(a2 * inv) | ((unsigned)f2bf(a3 * inv) << 16));
    o.z = (int)((unsigned)f2bf(a4 * inv) | ((unsigned)f2bf(a5 * inv) << 16));
    o.w = (int)((unsigned)f2bf(a6 * inv) | ((unsigned)f2bf(a7 * inv) << 16));
    *(int4v*)(smb + (size_t)e * H + lane * 8) = o;
}

// ---------------- fallback prep (small-ws path) ----------------
__global__ void prep_all(const float* __restrict__ Wm, const float* __restrict__ Wg,
                         const float* __restrict__ Wu,
                         ushort_t* __restrict__ Wmt, ushort_t* __restrict__ Wgt,
                         ushort_t* __restrict__ Wut, int* __restrict__ imap, int R) {
    size_t gtid = (size_t)blockIdx.x * blockDim.x + threadIdx.x;
    size_t stride = (size_t)gridDim.x * blockDim.x;
    for (size_t i = gtid; i < 65536; i += stride) {
        int n = (int)(i >> 8), k = (int)(i & 255);
        Wmt[i] = f2bf(Wm[(size_t)k * 256 + n]);
        Wut[i] = f2bf(Wu[(size_t)k * 256 + n]);
    }
    for (size_t i = gtid; i < 131072; i += stride) {
        int n = (int)(i >> 9), k = (int)(i & 511);
        Wgt[i] = f2bf(Wg[(size_t)k * 256 + n]);
    }
    for (size_t i = gtid; i < (size_t)R; i += stride) imap[i] = -1;
}

__global__ void imap_scatter(const int* __restrict__ tgt, int* __restrict__ imap, int E) {
    int e = blockIdx.x * 256 + threadIdx.x;
    if (e < E) imap[tgt[e]] = e;
}

// fallback: fp32 gather (small-ws path)
__global__ __launch_bounds__(256) void seg_mean_f32w(const float* __restrict__ x,
                                                     const int* __restrict__ ptr,
                                                     const int* __restrict__ src,
                                                     ushort_t* __restrict__ smb, int E) {
    int e = blockIdx.x * 4 + (threadIdx.x >> 6);
    if (e >= E) return;
    int lane = threadIdx.x & 63;
    int s = ptr[e], t = ptr[e + 1];
    float a0 = 0.f, a1 = 0.f, a2 = 0.f, a3 = 0.f;
    int i = s;
    for (; i + 4 <= t; i += 4) {
        float4 v0 = *(const float4*)(x + (size_t)src[i + 0] * H + lane * 4);
        float4 v1 = *(const float4*)(x + (size_t)src[i + 1] * H + lane * 4);
        float4 v2 = *(const float4*)(x + (size_t)src[i + 2] * H + lane * 4);
        float4 v3 = *(const float4*)(x + (size_t)src[i + 3] * H + lane * 4);
        a0 += v0.x + v1.x + v2.x + v3.x;
        a1 += v0.y + v1.y + v2.y + v3.y;
        a2 += v0.z + v1.z + v2.z + v3.z;
        a3 += v0.w + v1.w + v2.w + v3.w;
    }
    for (; i < t; ++i) {
        float4 v = *(const float4*)(x + (size_t)src[i] * H + lane * 4);
        a0 += v.x; a1 += v.y; a2 += v.z; a3 += v.w;
    }
    float inv = 1.f / (float)(t - s);
    uint2v o;
    o.x = (unsigned)f2bf(a0 * inv) | ((unsigned)f2bf(a1 * inv) << 16);
    o.y = (unsigned)f2bf(a2 * inv) | ((unsigned)f2bf(a3 * inv) << 16);
    *(uint2v*)(smb + (size_t)e * H + lane * 4) = o;
}

// reg-stage chunk loader for the fp32 fallback path only
#define LOADA_CHUNK_F(k0v, d)                                                            \
    do {                                                                                 \
        if constexpr (MODE == 1) {                                                       \
            if ((k0v) < 256) d = pack_f32x8_bf16(pXf + (k0v));                           \
            else             d = *(const int4v*)(pA + ((k0v) - 256));                    \
        } else {                                                                         \
            if (!useF) d = *(const int4v*)(p2 + (k0v));                                  \
            else       d = pack_f32x8_bf16(p2f + (k0v));                                 \
        }                                                                                \
    } while (0)

// stage one K-tile (3 glds16) into ring buffer bufv  [GL modes only]
#define STAGE_GL(k0v, bufv)                                                              \
    do {                                                                                 \
        glds16(bSrc0 + (k0v), (char*)&Bs[bufv][0] + tid * 16);                           \
        glds16(bSrc1 + (k0v), (char*)&Bs[bufv][0] + (tid + 512) * 16);                   \
        if constexpr (MODE == 1) {                                                       \
            const ushort_t* s_ = ((k0v) < 256) ? (aP0 + (k0v)) : (aP1 + (k0v));          \
            glds16(s_, (char*)&As[bufv][0] + tid * 16);                                  \
        } else {                                                                         \
            glds16(aP0 + (k0v), (char*)&As[bufv][0] + tid * 16);                         \
        }                                                                                \
    } while (0)

// one K-tile of MFMAs from ring buffer bufv
#define COMPUTE_GL(bufv)                                                                 \
    do {                                                                                 \
        const char* aBase = (const char*)&As[bufv][0];                                   \
        const char* bBase = (const char*)&Bs[bufv][0];                                   \
        const int kg = lane >> 4;                                                        \
        short8 a0, a1, a2, a3;                                                           \
        int r0 = wr * 64 + (lane & 15);                                                  \
        int r1 = r0 + 16, r2 = r0 + 32, r3 = r0 + 48;                                    \
        a0 = *(const short8*)(aBase + (r0 * 4 + (kg ^ ((r0 >> 1) & 3))) * 16);           \
        a1 = *(const short8*)(aBase + (r1 * 4 + (kg ^ ((r1 >> 1) & 3))) * 16);           \
        a2 = *(const short8*)(aBase + (r2 * 4 + (kg ^ ((r2 >> 1) & 3))) * 16);           \
        a3 = *(const short8*)(aBase + (r3 * 4 + (kg ^ ((r3 >> 1) & 3))) * 16);           \
        _Pragma("unroll")                                                                \
        for (int fn = 0; fn < 4; ++fn) {                                                 \
            int cn = wc * 64 + fn * 16 + (lane & 15);                                    \
            short8 b = *(const short8*)(bBase + (cn * 4 + (kg ^ ((cn >> 1) & 3))) * 16); \
            acc[0][fn] = __builtin_amdgcn_mfma_f32_16x16x32_bf16(a0, b, acc[0][fn], 0, 0, 0); \
            acc[1][fn] = __builtin_amdgcn_mfma_f32_16x16x32_bf16(a1, b, acc[1][fn], 0, 0, 0); \
            acc[2][fn] = __builtin_amdgcn_mfma_f32_16x16x32_bf16(a2, b, acc[2][fn], 0, 0, 0); \
            acc[3][fn] = __builtin_amdgcn_mfma_f32_16x16x32_bf16(a3, b, acc[3][fn], 0, 0, 0); \
        }                                                                                \
    } while (0)

// ---------------- full-N MFMA GEMM (8 waves, 128x256 tile) ----------------
// GL modes (0/3, 1&XB): 3-buffer LDS ring + raw s_barrier + counted vmcnt(3).
// Fallback modes keep the proven 2-buffer __syncthreads loop.
template<int MODE, int KTOT, bool XB>
__global__ __launch_bounds__(512, 4) void wgemm(
    const ushort_t* __restrict__ Abf,
    const float* __restrict__ Xf,
    const ushort_t* __restrict__ Xb,
    const ushort_t* __restrict__ Aux,
    const int* __restrict__ Idx,
    const float* __restrict__ Hew,
    const ushort_t* __restrict__ Wt,     // [256][KTOT] bf16 (pre-transposed)
    const float* __restrict__ Bias,      // [256] fp32
    ushort_t* __restrict__ OutB,
    float* __restrict__ OutF,
    int M)
{
    constexpr int NT = KTOT / 32;
    constexpr bool GL = (MODE == 0 || MODE == 3 || (MODE == 1 && XB));
    const int m0 = blockIdx.x * 128;
    const int tid = threadIdx.x;
    const int wv = tid >> 6;
    const int lane = tid & 63;
    const int wr = wv >> 2, wc = wv & 3;    // waves 2 (rows) x 4 (cols)

    __shared__ __align__(16) ushort_t As[3][128 * 32];
    __shared__ __align__(16) ushort_t Bs[3][256 * 32];

    const int aRow  = tid >> 2;
    const int sl    = tid & 3;
    const int aCc   = sl ^ ((aRow >> 1) & 3);
    const int bCol0 = tid >> 2;
    const int bCol1 = bCol0 + 128;
    const int bCc0  = sl ^ ((bCol0 >> 1) & 3);
    const int bCc1  = sl ^ ((bCol1 >> 1) & 3);

    const ushort_t* bSrc0 = Wt + (size_t)bCol0 * KTOT + bCc0 * 8;
    const ushort_t* bSrc1 = Wt + (size_t)bCol1 * KTOT + bCc1 * 8;

    int r = m0 + aRow; if (r > M - 1) r = M - 1;

    const ushort_t* aP0 = nullptr;
    const ushort_t* aP1 = nullptr;
    const float* pXf = nullptr; const ushort_t* pA = nullptr;
    const ushort_t* p2 = nullptr; const float* p2f = nullptr;
    bool useF = false;
    if constexpr (MODE == 0 || MODE == 3) {
        aP0 = Abf + (size_t)r * KTOT + aCc * 8;
    } else if constexpr (MODE == 1) {
        int tr = Idx[r];
        if constexpr (XB) {
            aP0 = Xb + (size_t)tr * 256 + aCc * 8;
            aP1 = Aux + (size_t)r * 256 + aCc * 8 - 256;
        } else {
            pXf = Xf + (size_t)tr * 256 + aCc * 8;
            pA  = Aux + (size_t)r * 256 + aCc * 8;
        }
    } else {
        int e = Idx[r];
        if (e >= 0) { p2 = Aux + (size_t)e * 256 + aCc * 8; useF = false; }
        else        { p2f = Xf + (size_t)r * 256 + aCc * 8; useF = true; }
    }

    f32x4 acc[4][4];
#pragma unroll
    for (int i = 0; i < 4; ++i)
#pragma unroll
        for (int j = 0; j < 4; ++j) acc[i][j] = (f32x4){0.f, 0.f, 0.f, 0.f};

    if constexpr (GL) {
        STAGE_GL(0, 0);
        STAGE_GL(32, 1);
#pragma unroll
        for (int kt = 0; kt < NT; ++kt) {
            if (kt == NT - 1) asm volatile("s_waitcnt vmcnt(0)" ::: "memory");
            else              asm volatile("s_waitcnt vmcnt(3)" ::: "memory");
            __builtin_amdgcn_s_barrier();
            if (kt + 2 < NT) {
                const int k0 = (kt + 2) * 32;
                const int bn = (kt + 2) % 3;
                STAGE_GL(k0, bn);
            }
            COMPUTE_GL(kt % 3);
        }
    } else {
        {
            int4v d0; LOADA_CHUNK_F(0, d0);
            *(int4v*)((char*)&As[0][0] + tid * 16) = d0;
        }
        glds16(bSrc0, (char*)&Bs[0][0] + tid * 16);
        glds16(bSrc1, (char*)&Bs[0][0] + (tid + 512) * 16);
#pragma unroll 2
        for (int kt = 0; kt < NT; ++kt) {
            __syncthreads();
            const int cur = kt & 1;
            const int nxt = cur ^ 1;
            const bool more = (kt + 1 < NT);
            int4v pf;
            if (more) {
                const int k0 = (kt + 1) * 32;
                glds16(bSrc0 + k0, (char*)&Bs[nxt][0] + tid * 16);
                glds16(bSrc1 + k0, (char*)&Bs[nxt][0] + (tid + 512) * 16);
                LOADA_CHUNK_F(k0, pf);
            }
            COMPUTE_GL(cur);
            if (more) {
                *(int4v*)((char*)&As[nxt][0] + tid * 16) = pf;
            }
        }
    }

    // ---- epilogue: C/D layout col=lane&15, row=(lane>>4)*4+i ----
#pragma unroll
    for (int fm = 0; fm < 4; ++fm) {
        int rbase = m0 + wr * 64 + fm * 16 + (lane >> 4) * 4;
#pragma unroll
        for (int fn = 0; fn < 4; ++fn) {
            int col = wc * 64 + fn * 16 + (lane & 15);
            float bia = Bias[col];
            f32x4 v = acc[fm][fn];
#pragma unroll
            for (int i = 0; i < 4; ++i) {
                int rg = rbase + i;
                if (rg < M) {
                    float z = v[i] + bia;
                    if constexpr (MODE == 0) {
                        OutB[(size_t)rg * 256 + col] = f2bf(z);
                    } else if constexpr (MODE == 1) {
                        float g = 1.f / (1.f + __expf(-z));
                        int tr = Idx[rg];
                        float tx;
                        if constexpr (XB) tx = bf2f(Xb[(size_t)tr * 256 + col]);
                        else              tx = Xf[(size_t)tr * 256 + col];
                        float m = bf2f(Aux[(size_t)rg * 256 + col]);
                        float u = tx + Hew[rg] * g * m;
                        if constexpr (XB) OutB[(size_t)tr * 256 + col] = f2bf(u);   // scatter into yb
                        else              OutB[(size_t)rg * 256 + col] = f2bf(u);
                    } else {
                        OutF[(size_t)rg * 256 + col] = fminf(fmaxf(z, 0.f), 1.f);
                    }
                }
            }
        }
    }
}

extern "C" void kernel_launch(void* const* d_in, const int* in_sizes, int n_in,
                              void* d_out, int out_size, void* d_ws, size_t ws_size,
                              hipStream_t stream) {
    const float* x      = (const float*)d_in[0];
    const int*   he_ptr = (const int*)d_in[1];
    const int*   he_src = (const int*)d_in[2];
    const int*   he_tgt = (const int*)d_in[3];
    const float* he_w   = (const float*)d_in[4];
    const float* W_msg  = (const float*)d_in[5];
    const float* b_msg  = (const float*)d_in[6];
    const float* W_gate = (const float*)d_in[7];
    const float* b_gate = (const float*)d_in[8];
    const float* W_upd  = (const float*)d_in[9];
    const float* b_upd  = (const float*)d_in[10];

    const int E = in_sizes[3];
    const int R = in_sizes[0] / H;

    const size_t wbytes = (size_t)(65536 + 131072 + 65536) * 2;
    const size_t needA = (size_t)R * H * 2 + (size_t)E * H * 2 * 2 + (size_t)R * 4 + wbytes;
    const bool bigws = ws_size >= needA;

    const int gE = (E + 127) / 128;
    const int gR = (R + 127) / 128;

    if (bigws) {
        char* ws = (char*)d_ws;
        ushort_t* yb   = (ushort_t*)ws;                                // R*256 bf16(x); becomes y after gemm2
        ushort_t* buf0 = yb + (size_t)R * H;                           // E*256: smb
        ushort_t* buf1 = buf0 + (size_t)E * H;                         // E*256: msgb
        ushort_t* Wmt  = (ushort_t*)(buf1 + (size_t)E * H);
        ushort_t* Wgt  = Wmt + 256 * 256;
        ushort_t* Wut  = Wgt + 256 * 512;

        // merged prep + seg-mean: conv blocks + gather blocks in one dispatch
        prep_seg<<<CONVB + (E + 7) / 8, 256, 0, stream>>>(
            W_msg, W_gate, W_upd, x, he_ptr, he_src,
            Wmt, Wgt, Wut, yb, buf0, R, E, (size_t)R * H / 8);

        // msg = smb @ Wm + b          (buf0 -> buf1)
        wgemm<0, 256, true><<<gE, 512, 0, stream>>>(buf0, nullptr, yb, nullptr, nullptr, nullptr,
                                                    Wmt, b_msg, buf1, nullptr, E);
        // gate + gated residual; u scattered into yb[tgt[e]]  -> yb becomes y
        wgemm<1, 512, true><<<gE, 512, 0, stream>>>(nullptr, nullptr, yb, buf1, he_tgt, he_w,
                                                    Wgt, b_gate, yb, nullptr, E);
        // out = clip(y @ Wu + b)      (yb linear -> d_out fp32)
        wgemm<3, 256, true><<<gR, 512, 0, stream>>>(yb, nullptr, nullptr, nullptr, nullptr, nullptr,
                                                    Wut, b_upd, nullptr, (float*)d_out, R);
    } else {
        char* ws = (char*)d_ws;
        ushort_t* buf0 = (ushort_t*)ws;
        ushort_t* buf1 = buf0 + (size_t)E * H;
        int*      imap = (int*)(buf1 + (size_t)E * H);
        ushort_t* Wmt  = (ushort_t*)((char*)imap + (size_t)R * 4);
        ushort_t* Wgt  = Wmt + 256 * 256;
        ushort_t* Wut  = Wgt + 256 * 512;

        prep_all<<<2048, 256, 0, stream>>>(W_msg, W_gate, W_upd, Wmt, Wgt, Wut, imap, R);
        imap_scatter<<<(E + 255) / 256, 256, 0, stream>>>(he_tgt, imap, E);
        seg_mean_f32w<<<(E + 3) / 4, 256, 0, stream>>>(x, he_ptr, he_src, buf0, E);

        wgemm<0, 256, false><<<gE, 512, 0, stream>>>(buf0, nullptr, nullptr, nullptr, nullptr, nullptr,
                                                     Wmt, b_msg, buf1, nullptr, E);
        wgemm<1, 512, false><<<gE, 512, 0, stream>>>(nullptr, x, nullptr, buf1, he_tgt, he_w,
                                                     Wgt, b_gate, buf0, nullptr, E);
        wgemm<2, 256, false><<<gR, 512, 0, stream>>>(nullptr, x, nullptr, buf0, imap, nullptr,
                                                     Wut, b_upd, nullptr, (float*)d_out, R);
    }
}

// Round 14
// 347.594 us; speedup vs baseline: 1.1717x; 1.1717x over previous
//
#include <hip/hip_runtime.h>
#include <math.h>

#define H 256

typedef __attribute__((ext_vector_type(8))) short short8;
typedef __attribute__((ext_vector_type(4))) float f32x4;
typedef __attribute__((ext_vector_type(4))) int int4v;
typedef __attribute__((ext_vector_type(2))) unsigned int uint2v;
typedef unsigned short ushort_t;

__device__ __forceinline__ float bf2f(unsigned short u) {
    union { unsigned int i; float f; } v; v.i = ((unsigned int)u) << 16; return v.f;
}
__device__ __forceinline__ unsigned short f2bf(float f) {
    union { float f; unsigned int i; } v; v.f = f;
    unsigned int r = v.i + 0x7FFFu + ((v.i >> 16) & 1u);   // RNE
    return (unsigned short)(r >> 16);
}
__device__ __forceinline__ void glds16(const void* g, void* l) {
    __builtin_amdgcn_global_load_lds((const __attribute__((address_space(1))) void*)g,
                                     (__attribute__((address_space(3))) void*)l, 16, 0, 0);
}
__device__ __forceinline__ int4v pack_f32x8_bf16(const float* p) {
    float4 f0 = *(const float4*)(p);
    float4 f1 = *(const float4*)(p + 4);
    int4v d;
    d.x = (int)((unsigned)f2bf(f0.x) | ((unsigned)f2bf(f0.y) << 16));
    d.y = (int)((unsigned)f2bf(f0.z) | ((unsigned)f2bf(f0.w) << 16));
    d.z = (int)((unsigned)f2bf(f1.x) | ((unsigned)f2bf(f1.y) << 16));
    d.w = (int)((unsigned)f2bf(f1.z) | ((unsigned)f2bf(f1.w) << 16));
    return d;
}

// ---------------- fused prep: weights transpose+cast, (opt) imap init, x->bf16 ----------------
__global__ void prep_all(const float* __restrict__ Wm, const float* __restrict__ Wg,
                         const float* __restrict__ Wu, const float* __restrict__ x,
                         ushort_t* __restrict__ Wmt, ushort_t* __restrict__ Wgt,
                         ushort_t* __restrict__ Wut, int* __restrict__ imap,
                         ushort_t* __restrict__ yb, int R, size_t n8) {
    size_t gtid = (size_t)blockIdx.x * blockDim.x + threadIdx.x;
    size_t stride = (size_t)gridDim.x * blockDim.x;
    for (size_t i = gtid; i < 65536; i += stride) {
        int n = (int)(i >> 8), k = (int)(i & 255);
        Wmt[i] = f2bf(Wm[(size_t)k * 256 + n]);
        Wut[i] = f2bf(Wu[(size_t)k * 256 + n]);
    }
    for (size_t i = gtid; i < 131072; i += stride) {
        int n = (int)(i >> 9), k = (int)(i & 511);
        Wgt[i] = f2bf(Wg[(size_t)k * 256 + n]);
    }
    if (imap) for (size_t i = gtid; i < (size_t)R; i += stride) imap[i] = -1;
    if (yb) for (size_t i = gtid; i < n8; i += stride)
        *(int4v*)(yb + i * 8) = pack_f32x8_bf16(x + i * 8);
}

__global__ void imap_scatter(const int* __restrict__ tgt, int* __restrict__ imap, int E) {
    int e = blockIdx.x * 256 + threadIdx.x;
    if (e < E) imap[tgt[e]] = e;
}

// ---------------- segment mean: half-wave per edge, 16B/lane, unroll-4 ----------------
__global__ __launch_bounds__(256) void seg_mean_bf16(const ushort_t* __restrict__ yb,
                                                     const int* __restrict__ ptr,
                                                     const int* __restrict__ src,
                                                     ushort_t* __restrict__ smb, int E) {
    int e = blockIdx.x * 8 + (threadIdx.x >> 5);
    if (e >= E) return;
    int lane = threadIdx.x & 31;
    const ushort_t* base = yb + lane * 8;
    int s = ptr[e], t = ptr[e + 1];
    float a0 = 0.f, a1 = 0.f, a2 = 0.f, a3 = 0.f, a4 = 0.f, a5 = 0.f, a6 = 0.f, a7 = 0.f;
    int i = s;
    for (; i + 4 <= t; i += 4) {
        int4v v0 = *(const int4v*)(base + (size_t)src[i + 0] * H);
        int4v v1 = *(const int4v*)(base + (size_t)src[i + 1] * H);
        int4v v2 = *(const int4v*)(base + (size_t)src[i + 2] * H);
        int4v v3 = *(const int4v*)(base + (size_t)src[i + 3] * H);
        a0 += bf2f((unsigned)v0.x & 0xffff) + bf2f((unsigned)v1.x & 0xffff) + bf2f((unsigned)v2.x & 0xffff) + bf2f((unsigned)v3.x & 0xffff);
        a1 += bf2f((unsigned)v0.x >> 16)    + bf2f((unsigned)v1.x >> 16)    + bf2f((unsigned)v2.x >> 16)    + bf2f((unsigned)v3.x >> 16);
        a2 += bf2f((unsigned)v0.y & 0xffff) + bf2f((unsigned)v1.y & 0xffff) + bf2f((unsigned)v2.y & 0xffff) + bf2f((unsigned)v3.y & 0xffff);
        a3 += bf2f((unsigned)v0.y >> 16)    + bf2f((unsigned)v1.y >> 16)    + bf2f((unsigned)v2.y >> 16)    + bf2f((unsigned)v3.y >> 16);
        a4 += bf2f((unsigned)v0.z & 0xffff) + bf2f((unsigned)v1.z & 0xffff) + bf2f((unsigned)v2.z & 0xffff) + bf2f((unsigned)v3.z & 0xffff);
        a5 += bf2f((unsigned)v0.z >> 16)    + bf2f((unsigned)v1.z >> 16)    + bf2f((unsigned)v2.z >> 16)    + bf2f((unsigned)v3.z >> 16);
        a6 += bf2f((unsigned)v0.w & 0xffff) + bf2f((unsigned)v1.w & 0xffff) + bf2f((unsigned)v2.w & 0xffff) + bf2f((unsigned)v3.w & 0xffff);
        a7 += bf2f((unsigned)v0.w >> 16)    + bf2f((unsigned)v1.w >> 16)    + bf2f((unsigned)v2.w >> 16)    + bf2f((unsigned)v3.w >> 16);
    }
    for (; i < t; ++i) {
        int4v v = *(const int4v*)(base + (size_t)src[i] * H);
        a0 += bf2f((unsigned)v.x & 0xffff); a1 += bf2f((unsigned)v.x >> 16);
        a2 += bf2f((unsigned)v.y & 0xffff); a3 += bf2f((unsigned)v.y >> 16);
        a4 += bf2f((unsigned)v.z & 0xffff); a5 += bf2f((unsigned)v.z >> 16);
        a6 += bf2f((unsigned)v.w & 0xffff); a7 += bf2f((unsigned)v.w >> 16);
    }
    float inv = 1.f / (float)(t - s);
    int4v o;
    o.x = (int)((unsigned)f2bf(a0 * inv) | ((unsigned)f2bf(a1 * inv) << 16));
    o.y = (int)((unsigned)f2bf(a2 * inv) | ((unsigned)f2bf(a3 * inv) << 16));
    o.z = (int)((unsigned)f2bf(a4 * inv) | ((unsigned)f2bf(a5 * inv) << 16));
    o.w = (int)((unsigned)f2bf(a6 * inv) | ((unsigned)f2bf(a7 * inv) << 16));
    *(int4v*)(smb + (size_t)e * H + lane * 8) = o;
}

// fallback: fp32 gather (small-ws path)
__global__ __launch_bounds__(256) void seg_mean_f32w(const float* __restrict__ x,
                                                     const int* __restrict__ ptr,
                                                     const int* __restrict__ src,
                                                     ushort_t* __restrict__ smb, int E) {
    int e = blockIdx.x * 4 + (threadIdx.x >> 6);
    if (e >= E) return;
    int lane = threadIdx.x & 63;
    int s = ptr[e], t = ptr[e + 1];
    float a0 = 0.f, a1 = 0.f, a2 = 0.f, a3 = 0.f;
    int i = s;
    for (; i + 4 <= t; i += 4) {
        float4 v0 = *(const float4*)(x + (size_t)src[i + 0] * H + lane * 4);
        float4 v1 = *(const float4*)(x + (size_t)src[i + 1] * H + lane * 4);
        float4 v2 = *(const float4*)(x + (size_t)src[i + 2] * H + lane * 4);
        float4 v3 = *(const float4*)(x + (size_t)src[i + 3] * H + lane * 4);
        a0 += v0.x + v1.x + v2.x + v3.x;
        a1 += v0.y + v1.y + v2.y + v3.y;
        a2 += v0.z + v1.z + v2.z + v3.z;
        a3 += v0.w + v1.w + v2.w + v3.w;
    }
    for (; i < t; ++i) {
        float4 v = *(const float4*)(x + (size_t)src[i] * H + lane * 4);
        a0 += v.x; a1 += v.y; a2 += v.z; a3 += v.w;
    }
    float inv = 1.f / (float)(t - s);
    uint2v o;
    o.x = (unsigned)f2bf(a0 * inv) | ((unsigned)f2bf(a1 * inv) << 16);
    o.y = (unsigned)f2bf(a2 * inv) | ((unsigned)f2bf(a3 * inv) << 16);
    *(uint2v*)(smb + (size_t)e * H + lane * 4) = o;
}

// reg-stage chunk loader for the fp32 fallback path only
#define LOADA_CHUNK_F(k0v, d)                                                            \
    do {                                                                                 \
        if constexpr (MODE == 1) {                                                       \
            if ((k0v) < 256) d = pack_f32x8_bf16(pXf + (k0v));                           \
            else             d = *(const int4v*)(pA + ((k0v) - 256));                    \
        } else {                                                                         \
            if (!useF) d = *(const int4v*)(p2 + (k0v));                                  \
            else       d = pack_f32x8_bf16(p2f + (k0v));                                 \
        }                                                                                \
    } while (0)

// stage one K-tile (3 glds16) into ring buffer bufv  [GL modes only]
#define STAGE_GL(k0v, bufv)                                                              \
    do {                                                                                 \
        glds16(bSrc0 + (k0v), (char*)&Bs[bufv][0] + tid * 16);                           \
        glds16(bSrc1 + (k0v), (char*)&Bs[bufv][0] + (tid + 512) * 16);                   \
        if constexpr (MODE == 1) {                                                       \
            const ushort_t* s_ = ((k0v) < 256) ? (aP0 + (k0v)) : (aP1 + (k0v));          \
            glds16(s_, (char*)&As[bufv][0] + tid * 16);                                  \
        } else {                                                                         \
            glds16(aP0 + (k0v), (char*)&As[bufv][0] + tid * 16);                         \
        }                                                                                \
    } while (0)

// one K-tile of MFMAs from ring buffer bufv
#define COMPUTE_GL(bufv)                                                                 \
    do {                                                                                 \
        const char* aBase = (const char*)&As[bufv][0];                                   \
        const char* bBase = (const char*)&Bs[bufv][0];                                   \
        const int kg = lane >> 4;                                                        \
        short8 a0, a1, a2, a3;                                                           \
        int r0 = wr * 64 + (lane & 15);                                                  \
        int r1 = r0 + 16, r2 = r0 + 32, r3 = r0 + 48;                                    \
        a0 = *(const short8*)(aBase + (r0 * 4 + (kg ^ ((r0 >> 1) & 3))) * 16);           \
        a1 = *(const short8*)(aBase + (r1 * 4 + (kg ^ ((r1 >> 1) & 3))) * 16);           \
        a2 = *(const short8*)(aBase + (r2 * 4 + (kg ^ ((r2 >> 1) & 3))) * 16);           \
        a3 = *(const short8*)(aBase + (r3 * 4 + (kg ^ ((r3 >> 1) & 3))) * 16);           \
        _Pragma("unroll")                                                                \
        for (int fn = 0; fn < 4; ++fn) {                                                 \
            int cn = wc * 64 + fn * 16 + (lane & 15);                                    \
            short8 b = *(const short8*)(bBase + (cn * 4 + (kg ^ ((cn >> 1) & 3))) * 16); \
            acc[0][fn] = __builtin_amdgcn_mfma_f32_16x16x32_bf16(a0, b, acc[0][fn], 0, 0, 0); \
            acc[1][fn] = __builtin_amdgcn_mfma_f32_16x16x32_bf16(a1, b, acc[1][fn], 0, 0, 0); \
            acc[2][fn] = __builtin_amdgcn_mfma_f32_16x16x32_bf16(a2, b, acc[2][fn], 0, 0, 0); \
            acc[3][fn] = __builtin_amdgcn_mfma_f32_16x16x32_bf16(a3, b, acc[3][fn], 0, 0, 0); \
        }                                                                                \
    } while (0)

// ---------------- full-N MFMA GEMM (8 waves, 128x256 tile) ----------------
// GL modes (0/3, 1&XB): 3-buffer LDS ring + raw s_barrier + counted vmcnt(3):
//   [vmcnt(3); barrier; issue stage(kt+2); compute(kt)]
// stage(kt+1)'s 3 loads stay in flight across the barrier (T4); stage(kt+2)
// writes the buffer last read by compute(kt-1), finished before this barrier.
// Fallback modes keep the proven 2-buffer __syncthreads loop.
template<int MODE, int KTOT, bool XB>
__global__ __launch_bounds__(512, 4) void wgemm(
    const ushort_t* __restrict__ Abf,
    const float* __restrict__ Xf,
    const ushort_t* __restrict__ Xb,
    const ushort_t* __restrict__ Aux,
    const int* __restrict__ Idx,
    const float* __restrict__ Hew,
    const ushort_t* __restrict__ Wt,     // [256][KTOT] bf16 (pre-transposed)
    const float* __restrict__ Bias,      // [256] fp32
    ushort_t* __restrict__ OutB,
    float* __restrict__ OutF,
    int M)
{
    constexpr int NT = KTOT / 32;
    constexpr bool GL = (MODE == 0 || MODE == 3 || (MODE == 1 && XB));
    const int m0 = blockIdx.x * 128;
    const int tid = threadIdx.x;
    const int wv = tid >> 6;
    const int lane = tid & 63;
    const int wr = wv >> 2, wc = wv & 3;    // waves 2 (rows) x 4 (cols)

    __shared__ __align__(16) ushort_t As[3][128 * 32];   // 24 KiB (GL uses 3, fallback 2)
    __shared__ __align__(16) ushort_t Bs[3][256 * 32];   // 48 KiB

    // ---- staging geometry (swizzle verified conflict-free in round 7) ----
    const int aRow  = tid >> 2;             // 0..127
    const int sl    = tid & 3;
    const int aCc   = sl ^ ((aRow >> 1) & 3);
    const int bCol0 = tid >> 2;
    const int bCol1 = bCol0 + 128;
    const int bCc0  = sl ^ ((bCol0 >> 1) & 3);
    const int bCc1  = sl ^ ((bCol1 >> 1) & 3);

    const ushort_t* bSrc0 = Wt + (size_t)bCol0 * KTOT + bCc0 * 8;
    const ushort_t* bSrc1 = Wt + (size_t)bCol1 * KTOT + bCc1 * 8;

    int r = m0 + aRow; if (r > M - 1) r = M - 1;

    // per-lane A source pointers
    const ushort_t* aP0 = nullptr;          // k domain [0,256)
    const ushort_t* aP1 = nullptr;          // k domain [256,512) (MODE1 only)
    const float* pXf = nullptr; const ushort_t* pA = nullptr;   // fp32 fallback
    const ushort_t* p2 = nullptr; const float* p2f = nullptr;
    bool useF = false;
    if constexpr (MODE == 0 || MODE == 3) {
        aP0 = Abf + (size_t)r * KTOT + aCc * 8;
    } else if constexpr (MODE == 1) {
        int tr = Idx[r];
        if constexpr (XB) {
            aP0 = Xb + (size_t)tr * 256 + aCc * 8;
            aP1 = Aux + (size_t)r * 256 + aCc * 8 - 256;   // +k0 with k0>=256 lands right
        } else {
            pXf = Xf + (size_t)tr * 256 + aCc * 8;
            pA  = Aux + (size_t)r * 256 + aCc * 8;
        }
    } else {
        int e = Idx[r];
        if (e >= 0) { p2 = Aux + (size_t)e * 256 + aCc * 8; useF = false; }
        else        { p2f = Xf + (size_t)r * 256 + aCc * 8; useF = true; }
    }

    f32x4 acc[4][4];
#pragma unroll
    for (int i = 0; i < 4; ++i)
#pragma unroll
        for (int j = 0; j < 4; ++j) acc[i][j] = (f32x4){0.f, 0.f, 0.f, 0.f};

    if constexpr (GL) {
        // ---- prologue: stage tiles 0,1 (6 loads in flight) ----
        STAGE_GL(0, 0);
        STAGE_GL(32, 1);
        // ---- K loop: counted-vmcnt pipeline, fully unrolled ----
#pragma unroll
        for (int kt = 0; kt < NT; ++kt) {
            if (kt == NT - 1) asm volatile("s_waitcnt vmcnt(0)" ::: "memory");
            else              asm volatile("s_waitcnt vmcnt(3)" ::: "memory");
            __builtin_amdgcn_s_barrier();
            if (kt + 2 < NT) {
                const int k0 = (kt + 2) * 32;
                const int bn = (kt + 2) % 3;
                STAGE_GL(k0, bn);
            }
            COMPUTE_GL(kt % 3);
        }
    } else {
        // ---- fallback: 2-buffer __syncthreads loop (round-10 structure) ----
        {
            int4v d0; LOADA_CHUNK_F(0, d0);
            *(int4v*)((char*)&As[0][0] + tid * 16) = d0;
        }
        glds16(bSrc0, (char*)&Bs[0][0] + tid * 16);
        glds16(bSrc1, (char*)&Bs[0][0] + (tid + 512) * 16);
#pragma unroll 2
        for (int kt = 0; kt < NT; ++kt) {
            __syncthreads();
            const int cur = kt & 1;
            const int nxt = cur ^ 1;
            const bool more = (kt + 1 < NT);
            int4v pf;
            if (more) {
                const int k0 = (kt + 1) * 32;
                glds16(bSrc0 + k0, (char*)&Bs[nxt][0] + tid * 16);
                glds16(bSrc1 + k0, (char*)&Bs[nxt][0] + (tid + 512) * 16);
                LOADA_CHUNK_F(k0, pf);
            }
            COMPUTE_GL(cur);
            if (more) {
                *(int4v*)((char*)&As[nxt][0] + tid * 16) = pf;
            }
        }
    }

    // ---- epilogue: C/D layout col=lane&15, row=(lane>>4)*4+i ----
#pragma unroll
    for (int fm = 0; fm < 4; ++fm) {
        int rbase = m0 + wr * 64 + fm * 16 + (lane >> 4) * 4;
#pragma unroll
        for (int fn = 0; fn < 4; ++fn) {
            int col = wc * 64 + fn * 16 + (lane & 15);
            float bia = Bias[col];
            f32x4 v = acc[fm][fn];
#pragma unroll
            for (int i = 0; i < 4; ++i) {
                int rg = rbase + i;
                if (rg < M) {
                    float z = v[i] + bia;
                    if constexpr (MODE == 0) {
                        OutB[(size_t)rg * 256 + col] = f2bf(z);
                    } else if constexpr (MODE == 1) {
                        float g = 1.f / (1.f + __expf(-z));
                        int tr = Idx[rg];
                        float tx;
                        if constexpr (XB) tx = bf2f(Xb[(size_t)tr * 256 + col]);
                        else              tx = Xf[(size_t)tr * 256 + col];
                        float m = bf2f(Aux[(size_t)rg * 256 + col]);
                        float u = tx + Hew[rg] * g * m;
                        if constexpr (XB) OutB[(size_t)tr * 256 + col] = f2bf(u);   // scatter into yb
                        else              OutB[(size_t)rg * 256 + col] = f2bf(u);
                    } else {
                        OutF[(size_t)rg * 256 + col] = fminf(fmaxf(z, 0.f), 1.f);
                    }
                }
            }
        }
    }
}

extern "C" void kernel_launch(void* const* d_in, const int* in_sizes, int n_in,
                              void* d_out, int out_size, void* d_ws, size_t ws_size,
                              hipStream_t stream) {
    const float* x      = (const float*)d_in[0];
    const int*   he_ptr = (const int*)d_in[1];
    const int*   he_src = (const int*)d_in[2];
    const int*   he_tgt = (const int*)d_in[3];
    const float* he_w   = (const float*)d_in[4];
    const float* W_msg  = (const float*)d_in[5];
    const float* b_msg  = (const float*)d_in[6];
    const float* W_gate = (const float*)d_in[7];
    const float* b_gate = (const float*)d_in[8];
    const float* W_upd  = (const float*)d_in[9];
    const float* b_upd  = (const float*)d_in[10];

    const int E = in_sizes[3];
    const int R = in_sizes[0] / H;

    const size_t wbytes = (size_t)(65536 + 131072 + 65536) * 2;
    const size_t needA = (size_t)R * H * 2 + (size_t)E * H * 2 * 2 + (size_t)R * 4 + wbytes;
    const bool bigws = ws_size >= needA;

    const int gE = (E + 127) / 128;
    const int gR = (R + 127) / 128;

    if (bigws) {
        char* ws = (char*)d_ws;
        ushort_t* yb   = (ushort_t*)ws;                                // R*256 bf16(x); becomes y after gemm2
        ushort_t* buf0 = yb + (size_t)R * H;                           // E*256: smb
        ushort_t* buf1 = buf0 + (size_t)E * H;                         // E*256: msgb
        ushort_t* Wmt  = (ushort_t*)(buf1 + (size_t)E * H);
        ushort_t* Wgt  = Wmt + 256 * 256;
        ushort_t* Wut  = Wgt + 256 * 512;

        prep_all<<<2048, 256, 0, stream>>>(W_msg, W_gate, W_upd, x,
                                           Wmt, Wgt, Wut, (int*)nullptr, yb, R, (size_t)R * H / 8);
        seg_mean_bf16<<<(E + 7) / 8, 256, 0, stream>>>(yb, he_ptr, he_src, buf0, E);

        // msg = smb @ Wm + b          (buf0 -> buf1)
        wgemm<0, 256, true><<<gE, 512, 0, stream>>>(buf0, nullptr, yb, nullptr, nullptr, nullptr,
                                                    Wmt, b_msg, buf1, nullptr, E);
        // gate + gated residual; u scattered into yb[tgt[e]]  -> yb becomes y
        wgemm<1, 512, true><<<gE, 512, 0, stream>>>(nullptr, nullptr, yb, buf1, he_tgt, he_w,
                                                    Wgt, b_gate, yb, nullptr, E);
        // out = clip(y @ Wu + b)      (yb linear -> d_out fp32)
        wgemm<3, 256, true><<<gR, 512, 0, stream>>>(yb, nullptr, nullptr, nullptr, nullptr, nullptr,
                                                    Wut, b_upd, nullptr, (float*)d_out, R);
    } else {
        char* ws = (char*)d_ws;
        ushort_t* buf0 = (ushort_t*)ws;
        ushort_t* buf1 = buf0 + (size_t)E * H;
        int*      imap = (int*)(buf1 + (size_t)E * H);
        ushort_t* Wmt  = (ushort_t*)((char*)imap + (size_t)R * 4);
        ushort_t* Wgt  = Wmt + 256 * 256;
        ushort_t* Wut  = Wgt + 256 * 512;

        prep_all<<<2048, 256, 0, stream>>>(W_msg, W_gate, W_upd, nullptr,
                                           Wmt, Wgt, Wut, imap, (ushort_t*)nullptr, R, 0);
        imap_scatter<<<(E + 255) / 256, 256, 0, stream>>>(he_tgt, imap, E);
        seg_mean_f32w<<<(E + 3) / 4, 256, 0, stream>>>(x, he_ptr, he_src, buf0, E);

        wgemm<0, 256, false><<<gE, 512, 0, stream>>>(buf0, nullptr, nullptr, nullptr, nullptr, nullptr,
                                                     Wmt, b_msg, buf1, nullptr, E);
        wgemm<1, 512, false><<<gE, 512, 0, stream>>>(nullptr, x, nullptr, buf1, he_tgt, he_w,
                                                     Wgt, b_gate, buf0, nullptr, E);
        wgemm<2, 256, false><<<gR, 512, 0, stream>>>(nullptr, x, nullptr, buf0, imap, nullptr,
                                                     Wut, b_upd, nullptr, (float*)d_out, R);
    }
}